// Round 10
// baseline (650.787 us; speedup 1.0000x reference)
//
#include <hip/hip_runtime.h>
#include <hip/hip_bf16.h>
#include <hip/hip_fp16.h>
#include <hip/hip_cooperative_groups.h>
#include <math.h>

namespace cg = cooperative_groups;

__device__ __forceinline__ float leaky02(float x) { return x > 0.f ? x : 0.2f * x; }

// K_build (cooperative, G=1024 blocks x 256): entire CSR build + node1 in one
// launch. P0: zero counts || node1. P1: dst-count atomics. P2: per-chunk sums
// (chunk CH<=64, wave 0). P3: wave 0 redundantly block-prefix-scans bsum +
// chunk scan -> offs/cursor. P4: scatter. 4 grid syncs.
__global__ void k_build(const float* __restrict__ x, const float* __restrict__ W1,
                        const float* __restrict__ att_s, const float* __restrict__ att_d,
                        __half* __restrict__ h1h, float* __restrict__ as1,
                        float* __restrict__ ad1,
                        const int* __restrict__ ei, int* __restrict__ counts,
                        int* __restrict__ bsum, int* __restrict__ offs,
                        int* __restrict__ cursor, int* __restrict__ srcs,
                        int N, int E, int CH) {
    cg::grid_group grid = cg::this_grid();
    const int G = gridDim.x;
    const int nthr = G * blockDim.x;
    const int tid = blockIdx.x * blockDim.x + threadIdx.x;
    const int lane = threadIdx.x & 63;
    const int b = blockIdx.x;

    // ---- P0: zero counts (grid-stride) + node1 (one wave per node) ----
    for (int i = tid; i < N; i += nthr) counts[i] = 0;
    {
        int gw = tid >> 6;
        int nw = nthr >> 6;
        int c = lane * 4;
        float4 w0 = *reinterpret_cast<const float4*>(&W1[c]);
        float4 w1 = *reinterpret_cast<const float4*>(&W1[256 + c]);
        float4 w2 = *reinterpret_cast<const float4*>(&W1[512 + c]);
        float4 as = *reinterpret_cast<const float4*>(&att_s[c]);
        float4 ad = *reinterpret_cast<const float4*>(&att_d[c]);
        for (int n = gw; n < N; n += nw) {
            float x0 = x[n * 3 + 0], x1 = x[n * 3 + 1], x2 = x[n * 3 + 2];
            float h0 = x0 * w0.x + x1 * w1.x + x2 * w2.x;
            float h1_ = x0 * w0.y + x1 * w1.y + x2 * w2.y;
            float h2_ = x0 * w0.z + x1 * w1.z + x2 * w2.z;
            float h3 = x0 * w0.w + x1 * w1.w + x2 * w2.w;
            union { __half2 h[2]; uint2 u; } pk;
            pk.h[0] = __floats2half2_rn(h0, h1_);
            pk.h[1] = __floats2half2_rn(h2_, h3);
            *reinterpret_cast<uint2*>(h1h + (size_t)n * 256 + c) = pk.u;
            float vs = h0 * as.x + h1_ * as.y + h2_ * as.z + h3 * as.w;
            float vd = h0 * ad.x + h1_ * ad.y + h2_ * ad.z + h3 * ad.w;
            #pragma unroll
            for (int m = 1; m < 8; m <<= 1) {
                vs += __shfl_xor(vs, m);
                vd += __shfl_xor(vd, m);
            }
            if ((lane & 7) == 0) {
                as1[n * 8 + (lane >> 3)] = vs;
                ad1[n * 8 + (lane >> 3)] = vd;
            }
        }
    }
    grid.sync();

    // ---- P1: dst-count atomics ----
    for (int t = tid; t < E; t += nthr) atomicAdd(&counts[ei[E + t]], 1);
    grid.sync();

    // ---- P2: per-chunk sum (wave 0; chunk size CH <= 64) ----
    if (threadIdx.x < 64) {
        int i = b * CH + lane;
        int c = (lane < CH && i < N) ? counts[i] + 1 : 0;   // +1 self-loop
        int s = c;
        #pragma unroll
        for (int m = 1; m < 64; m <<= 1) s += __shfl_xor(s, m);
        if (lane == 0) bsum[b] = s;
    }
    grid.sync();

    // ---- P3: wave 0: redundant exclusive prefix over bsum + chunk scan ----
    if (threadIdx.x < 64) {
        int P = 0;
        for (int base = 0; base < G; base += 64) {
            int idx = base + lane;
            int v = (idx < b) ? bsum[idx] : 0;
            #pragma unroll
            for (int m = 1; m < 64; m <<= 1) v += __shfl_xor(v, m);
            P += v;
        }
        int i = b * CH + lane;
        int c = (lane < CH && i < N) ? counts[i] + 1 : 0;
        int incl = c;
        #pragma unroll
        for (int off = 1; off < 64; off <<= 1) {
            int tv = __shfl_up(incl, off);
            if (lane >= off) incl += tv;
        }
        int excl = P + incl - c;
        if (lane < CH && i < N) {
            cursor[i] = excl;
            offs[i + 1] = excl + c;
        }
        if (b == 0 && lane == 0) offs[0] = 0;
    }
    grid.sync();

    // ---- P4: scatter (grid-stride) ----
    for (int t = tid; t < E + N; t += nthr) {
        if (t < E) {
            int s = ei[t], d = ei[E + t];
            int pos = atomicAdd(&cursor[d], 1);
            srcs[pos] = s;
        } else {
            int i = t - E;
            int pos = atomicAdd(&cursor[i], 1);
            srcs[pos] = i;  // self loop
        }
    }
}

// K_agg1 (28 VGPR / 70% occ): one wave per dst node. Lane owns 4 channels
// (head = lane>>3). p-sharing: lane (po=lane>>3, ph=lane&7) computes
// p8[j] = exp(leaky(...)) for its 8 edges; consumers fetch via convergent
// shfl. Single pass (logits O(1)). fp16 out.
__global__ void k_agg1(const __half* __restrict__ h1h, const float* __restrict__ as1,
                       const float* __restrict__ ad1, const float* __restrict__ b1,
                       const int* __restrict__ offs, const int* __restrict__ srcs,
                       __half* __restrict__ feath, int N) {
    int wid = threadIdx.x >> 6;
    int d = blockIdx.x * 4 + wid;
    if (d >= N) return;
    int lane = threadIdx.x & 63;
    int head = lane >> 3;
    int po = lane >> 3;
    int ph = lane & 7;
    float ad_p = ad1[d * 8 + ph];
    int beg = offs[d], end = offs[d + 1];
    float denom = 0.f, a0 = 0.f, a1 = 0.f, a2 = 0.f, a3 = 0.f;
    for (int cb = beg; cb < end; cb += 64) {
        int idx = cb + lane;
        int myS = srcs[idx < end ? idx : end - 1];
        int cnt = min(64, end - cb);   // wave-uniform
        float p8[8];
        #pragma unroll
        for (int j = 0; j < 8; ++j) {
            int s = __shfl(myS, po * 8 + j);
            p8[j] = __expf(leaky02(as1[s * 8 + ph] + ad_p));
        }
        for (int kb = 0; kb < cnt; kb += 8) {
            #pragma unroll
            for (int j = 0; j < 8; ++j) {
                int k = kb + j;            // wave-uniform
                if (k < cnt) {             // uniform branch: convergent shfls
                    int s = __shfl(myS, k);
                    float p = __shfl(p8[j], kb + head);
                    denom += p;
                    uint2 raw = *reinterpret_cast<const uint2*>(
                        h1h + (size_t)s * 256 + lane * 4);
                    union { unsigned u; __half2 h; } u0, u1;
                    u0.u = raw.x; u1.u = raw.y;
                    float2 f01 = __half22float2(u0.h);
                    float2 f23 = __half22float2(u1.h);
                    a0 += p * f01.x; a1 += p * f01.y;
                    a2 += p * f23.x; a3 += p * f23.y;
                }
            }
        }
    }
    float inv = 1.f / (denom + 1e-16f);
    int c = lane * 4;
    float4 bv = *reinterpret_cast<const float4*>(&b1[c]);
    float r0 = a0 * inv + bv.x;
    float r1 = a1 * inv + bv.y;
    float r2 = a2 * inv + bv.z;
    float r3 = a3 * inv + bv.w;
    r0 = r0 > 0.f ? r0 : (__expf(r0) - 1.f);
    r1 = r1 > 0.f ? r1 : (__expf(r1) - 1.f);
    r2 = r2 > 0.f ? r2 : (__expf(r2) - 1.f);
    r3 = r3 > 0.f ? r3 : (__expf(r3) - 1.f);
    union { __half2 h[2]; uint2 u; } pk;
    pk.h[0] = __floats2half2_rn(r0, r1);
    pk.h[1] = __floats2half2_rn(r2, r3);
    *reinterpret_cast<uint2*>(feath + (size_t)d * 256 + c) = pk.u;
}

// K_node2: one wave per node; W2 in LDS (swizzled, 2-way max conflict).
__global__ void k_node2(const __half* __restrict__ feath, const float* __restrict__ W2,
                        const float* __restrict__ att_s2, const float* __restrict__ att_d2,
                        __half* __restrict__ h2h, float* __restrict__ as2,
                        float* __restrict__ ad2, int N) {
    __shared__ float w_lds[4096];
    int t = threadIdx.x;
    {
        int k = t;
        const float4* src = reinterpret_cast<const float4*>(&W2[k * 16]);
        int base = ((k >> 7) << 11) + ((k & 63) << 5) + (((k >> 6) & 1) << 4);
        float4 v0 = src[0], v1 = src[1], v2 = src[2], v3 = src[3];
        *reinterpret_cast<float4*>(&w_lds[base + 0]) = v0;
        *reinterpret_cast<float4*>(&w_lds[base + 4]) = v1;
        *reinterpret_cast<float4*>(&w_lds[base + 8]) = v2;
        *reinterpret_cast<float4*>(&w_lds[base + 12]) = v3;
    }
    __syncthreads();
    int wid = t >> 6;
    int n = blockIdx.x * 4 + wid;
    if (n >= N) return;
    int lane = t & 63;
    int o = lane & 15, q = lane >> 4;
    const __half* fr = feath + (size_t)n * 256 + q * 64;
    const float* w = w_lds + ((q >> 1) << 11) + ((q & 1) << 4) + o;
    float acc = 0.f;
    #pragma unroll
    for (int jj = 0; jj < 8; ++jj) {
        union { uint4 u; __half2 h[4]; } v;
        v.u = *reinterpret_cast<const uint4*>(fr + jj * 8);
        #pragma unroll
        for (int tt = 0; tt < 4; ++tt) {
            float2 f = __half22float2(v.h[tt]);
            acc += f.x * w[(jj * 8 + tt * 2 + 0) * 32];
            acc += f.y * w[(jj * 8 + tt * 2 + 1) * 32];
        }
    }
    acc += __shfl_xor(acc, 16);
    acc += __shfl_xor(acc, 32);
    if (lane < 16) h2h[n * 16 + o] = __float2half(acc);
    float ts = acc * att_s2[o], td = acc * att_d2[o];
    #pragma unroll
    for (int m = 1; m < 16; m <<= 1) {
        ts += __shfl_xor(ts, m);
        td += __shfl_xor(td, m);
    }
    if (lane == 0) { as2[n] = ts; ad2[n] = td; }
}

// K_agg2: one wave per dst. 16 edge-groups x 4 lanes owning 4 channels each.
__global__ void k_agg2(const __half* __restrict__ h2h, const float* __restrict__ as2,
                       const float* __restrict__ ad2, const float* __restrict__ b2,
                       const int* __restrict__ offs, const int* __restrict__ srcs,
                       float* __restrict__ out, int N) {
    int wid = threadIdx.x >> 6;
    int d = blockIdx.x * 4 + wid;
    if (d >= N) return;
    int lane = threadIdx.x & 63;
    int cl = lane & 3, eg = lane >> 2;
    float ad = ad2[d];
    int beg = offs[d], end = offs[d + 1];
    float denom = 0.f, a0 = 0.f, a1 = 0.f, a2 = 0.f, a3 = 0.f;
    for (int cb = beg; cb < end; cb += 64) {
        int idx = cb + lane;
        int myS = srcs[idx < end ? idx : end - 1];
        #pragma unroll
        for (int cc = 0; cc < 4; ++cc) {
            int s = __shfl(myS, cc * 16 + eg);   // convergent
            int epos = cb + cc * 16 + eg;
            if (epos < end) {
                float e = leaky02(as2[s] + ad);
                float p = __expf(e);
                denom += p;
                uint2 raw = *reinterpret_cast<const uint2*>(h2h + (size_t)s * 16 + cl * 4);
                union { unsigned u; __half2 h; } u0, u1;
                u0.u = raw.x; u1.u = raw.y;
                float2 f01 = __half22float2(u0.h);
                float2 f23 = __half22float2(u1.h);
                a0 += p * f01.x; a1 += p * f01.y; a2 += p * f23.x; a3 += p * f23.y;
            }
        }
    }
    #pragma unroll
    for (int m = 4; m < 64; m <<= 1) {
        denom += __shfl_xor(denom, m);
        a0 += __shfl_xor(a0, m);
        a1 += __shfl_xor(a1, m);
        a2 += __shfl_xor(a2, m);
        a3 += __shfl_xor(a3, m);
    }
    if (eg == 0) {
        float inv = 1.f / (denom + 1e-16f);
        int c = cl * 4;
        float4 r;
        r.x = a0 * inv + b2[c + 0];
        r.y = a1 * inv + b2[c + 1];
        r.z = a2 * inv + b2[c + 2];
        r.w = a3 * inv + b2[c + 3];
        *reinterpret_cast<float4*>(&out[d * 16 + c]) = r;
    }
}

extern "C" void kernel_launch(void* const* d_in, const int* in_sizes, int n_in,
                              void* d_out, int out_size, void* d_ws, size_t ws_size,
                              hipStream_t stream) {
    const float* x       = (const float*)d_in[0];
    const int*   ei      = (const int*)d_in[1];
    const float* W1      = (const float*)d_in[2];
    const float* att_s1  = (const float*)d_in[3];
    const float* att_d1  = (const float*)d_in[4];
    const float* b1      = (const float*)d_in[5];
    const float* W2      = (const float*)d_in[6];
    const float* att_s2  = (const float*)d_in[7];
    const float* att_d2  = (const float*)d_in[8];
    const float* b2      = (const float*)d_in[9];
    float* out = (float*)d_out;

    const int N = in_sizes[0] / 3;
    const int E = in_sizes[1] / 2;
    const int Etot = E + N;
    const int G = 1024;                 // coop grid (co-resident: 4 blocks/CU)
    const int CH = (N + G - 1) / G;     // nodes per block chunk (<= 64)

    // carve workspace (16B aligned slices)
    char* w = (char*)d_ws;
    auto alloc = [&](size_t bytes) -> void* {
        void* p = (void*)w;
        w += (bytes + 15) & ~(size_t)15;
        return p;
    };
    int* counts   = (int*)alloc((size_t)N * 4);
    int* offs     = (int*)alloc((size_t)(N + 1) * 4);
    int* cursor   = (int*)alloc((size_t)N * 4);
    int* srcs     = (int*)alloc((size_t)Etot * 4);
    int* bsum     = (int*)alloc((size_t)(G + 1) * 4);
    __half* h1h   = (__half*)alloc((size_t)N * 256 * 2);
    float* as1    = (float*)alloc((size_t)N * 8 * 4);
    float* ad1    = (float*)alloc((size_t)N * 8 * 4);
    __half* feath = (__half*)alloc((size_t)N * 256 * 2);
    __half* h2h   = (__half*)alloc((size_t)N * 16 * 2);
    float* as2    = (float*)alloc((size_t)N * 4);
    float* ad2    = (float*)alloc((size_t)N * 4);
    (void)ws_size; (void)n_in; (void)out_size;

    const int B = 256;

    void* args[] = {
        (void*)&x, (void*)&W1, (void*)&att_s1, (void*)&att_d1,
        (void*)&h1h, (void*)&as1, (void*)&ad1,
        (void*)&ei, (void*)&counts, (void*)&bsum, (void*)&offs,
        (void*)&cursor, (void*)&srcs,
        (void*)&N, (void*)&E, (void*)&CH
    };
    hipLaunchCooperativeKernel((const void*)k_build, dim3(G), dim3(B),
                               args, 0, stream);
    hipLaunchKernelGGL(k_agg1, dim3((N + 3) / 4), dim3(B), 0, stream,
                       h1h, as1, ad1, b1, offs, srcs, feath, N);
    hipLaunchKernelGGL(k_node2, dim3((N + 3) / 4), dim3(B), 0, stream,
                       feath, W2, att_s2, att_d2, h2h, as2, ad2, N);
    hipLaunchKernelGGL(k_agg2, dim3((N + 3) / 4), dim3(B), 0, stream,
                       h2h, as2, ad2, b2, offs, srcs, out, N);
}

// Round 11
// 236.671 us; speedup vs baseline: 2.7498x; 2.7498x over previous
//
#include <hip/hip_runtime.h>
#include <hip/hip_bf16.h>
#include <hip/hip_fp16.h>
#include <math.h>

__device__ __forceinline__ float leaky02(float x) { return x > 0.f ? x : 0.2f * x; }

// K_prep: fat kernel. Blocks [0,NB1): node1 transform (one wave per node,
// lane owns channels [4*lane..4*lane+3]). Blocks [NB1,...): edge dst count.
__global__ void k_prep(const float* __restrict__ x, const float* __restrict__ W1,
                       const float* __restrict__ att_s, const float* __restrict__ att_d,
                       __half* __restrict__ h1h, float* __restrict__ as1,
                       float* __restrict__ ad1,
                       const int* __restrict__ ei, int* __restrict__ counts,
                       int N, int E, int NB1) {
    int b = blockIdx.x;
    if (b < NB1) {
        int wid = threadIdx.x >> 6;
        int n = b * 4 + wid;
        if (n >= N) return;
        int lane = threadIdx.x & 63;
        int c = lane * 4;
        float x0 = x[n * 3 + 0], x1 = x[n * 3 + 1], x2 = x[n * 3 + 2];
        float4 w0 = *reinterpret_cast<const float4*>(&W1[c]);
        float4 w1 = *reinterpret_cast<const float4*>(&W1[256 + c]);
        float4 w2 = *reinterpret_cast<const float4*>(&W1[512 + c]);
        float h0 = x0 * w0.x + x1 * w1.x + x2 * w2.x;
        float h1_ = x0 * w0.y + x1 * w1.y + x2 * w2.y;
        float h2_ = x0 * w0.z + x1 * w1.z + x2 * w2.z;
        float h3 = x0 * w0.w + x1 * w1.w + x2 * w2.w;
        union { __half2 h[2]; uint2 u; } pk;
        pk.h[0] = __floats2half2_rn(h0, h1_);
        pk.h[1] = __floats2half2_rn(h2_, h3);
        *reinterpret_cast<uint2*>(h1h + (size_t)n * 256 + c) = pk.u;
        float4 as = *reinterpret_cast<const float4*>(&att_s[c]);
        float4 ad = *reinterpret_cast<const float4*>(&att_d[c]);
        float vs = h0 * as.x + h1_ * as.y + h2_ * as.z + h3 * as.w;
        float vd = h0 * ad.x + h1_ * ad.y + h2_ * ad.z + h3 * ad.w;
        #pragma unroll
        for (int m = 1; m < 8; m <<= 1) {
            vs += __shfl_xor(vs, m);
            vd += __shfl_xor(vd, m);
        }
        if ((lane & 7) == 0) {
            as1[n * 8 + (lane >> 3)] = vs;
            ad1[n * 8 + (lane >> 3)] = vd;
        }
    } else {
        int t = (b - NB1) * blockDim.x + threadIdx.x;
        if (t < E) atomicAdd(&counts[ei[E + t]], 1);  // dst row
    }
}

// per-1024-chunk block sums of (counts[i] + 1)  [+1 = self-loop]
__global__ void k_bsum(const int* __restrict__ counts, int* __restrict__ bsum, int N) {
    __shared__ int wsum[4];
    int b = blockIdx.x;
    int t = threadIdx.x;
    int s = 0;
    #pragma unroll
    for (int j = 0; j < 4; ++j) {
        int i = b * 1024 + j * 256 + t;
        if (i < N) s += counts[i] + 1;
    }
    #pragma unroll
    for (int m = 1; m < 64; m <<= 1) s += __shfl_xor(s, m);
    int lane = t & 63, wid = t >> 6;
    if (lane == 0) wsum[wid] = s;
    __syncthreads();
    if (t == 0) bsum[b] = wsum[0] + wsum[1] + wsum[2] + wsum[3];
}

// per-block offsets + cursor (fused); block prefix computed in-wave from bsum.
__global__ void k_offs(const int* __restrict__ counts, const int* __restrict__ bsum,
                       int* __restrict__ offs, int* __restrict__ cursor, int N, int NB) {
    __shared__ int wsum[4];
    int b = blockIdx.x;
    int t = threadIdx.x;
    int lane = t & 63, wid = t >> 6;
    int P = 0;
    for (int base = 0; base < NB; base += 64) {
        int i = base + lane;
        int v = (i < NB && i < b) ? bsum[i] : 0;
        #pragma unroll
        for (int m = 1; m < 64; m <<= 1) v += __shfl_xor(v, m);
        P += v;
    }
    int i0 = b * 1024 + t * 4;
    int c0 = 0, c1 = 0, c2 = 0, c3 = 0;
    if (i0 + 3 < N) {
        int4 cv = *reinterpret_cast<const int4*>(&counts[i0]);
        c0 = cv.x + 1; c1 = cv.y + 1; c2 = cv.z + 1; c3 = cv.w + 1;
    } else {
        if (i0 + 0 < N) c0 = counts[i0 + 0] + 1;
        if (i0 + 1 < N) c1 = counts[i0 + 1] + 1;
        if (i0 + 2 < N) c2 = counts[i0 + 2] + 1;
        if (i0 + 3 < N) c3 = counts[i0 + 3] + 1;
    }
    int tsum = c0 + c1 + c2 + c3;
    int incl = tsum;
    #pragma unroll
    for (int off = 1; off < 64; off <<= 1) {
        int tv = __shfl_up(incl, off);
        if (lane >= off) incl += tv;
    }
    if (lane == 63) wsum[wid] = incl;
    __syncthreads();
    int woff = 0;
    for (int w = 0; w < wid; ++w) woff += wsum[w];
    int base = P + woff + incl - tsum;
    int p0 = base;
    int p1 = p0 + c0;
    int p2 = p1 + c1;
    int p3 = p2 + c2;
    int p4 = p3 + c3;
    if (i0 + 0 < N) { cursor[i0 + 0] = p0; offs[i0 + 1] = p1; }
    if (i0 + 1 < N) { cursor[i0 + 1] = p1; offs[i0 + 2] = p2; }
    if (i0 + 2 < N) { cursor[i0 + 2] = p2; offs[i0 + 3] = p3; }
    if (i0 + 3 < N) { cursor[i0 + 3] = p3; offs[i0 + 4] = p4; }
    if (b == 0 && t == 0) offs[0] = 0;
}

__global__ void k_scatter(const int* __restrict__ ei, int* cursor, int* srcs, int E, int N) {
    int t = blockIdx.x * blockDim.x + threadIdx.x;
    if (t < E) {
        int s = ei[t], d = ei[E + t];
        int pos = atomicAdd(&cursor[d], 1);
        srcs[pos] = s;
    } else if (t < E + N) {
        int i = t - E;
        int pos = atomicAdd(&cursor[i], 1);
        srcs[pos] = i;  // self loop
    }
}

// K_agg1n2: agg1 (proven 28-VGPR main loop) + node2 tail via LDS.
// Entry: all 256 threads stage W2 (16KB, swizzled: pos(k,o) = (k>>7)*2048 +
// (k&63)*32 + ((k>>6)&1)*16 + o -> 2-way max conflict) + one barrier.
// Main: one wave per dst; lane owns 4 channels; p-sharing via convergent shfl.
// Tail: lane writes feat (f32) to feat_lds[wid][256] (wave-private -> no
// barrier), then node2 inner loop: feat via LDS broadcast (free), W2 at
// 2-way (free), shfl-reduce -> h2h/as2/ad2. feath never exists in memory.
__global__ void k_agg1n2(const __half* __restrict__ h1h, const float* __restrict__ as1,
                         const float* __restrict__ ad1, const float* __restrict__ b1,
                         const float* __restrict__ W2, const float* __restrict__ att_s2,
                         const float* __restrict__ att_d2,
                         const int* __restrict__ offs, const int* __restrict__ srcs,
                         __half* __restrict__ h2h, float* __restrict__ as2,
                         float* __restrict__ ad2, int N) {
    __shared__ float w_lds[4096];
    __shared__ float feat_lds[1024];   // 4 waves x 256 channels
    int t = threadIdx.x;
    {   // thread t stages W2 row k=t into the swizzled slot
        int k = t;
        const float4* src = reinterpret_cast<const float4*>(&W2[k * 16]);
        int base = ((k >> 7) << 11) + ((k & 63) << 5) + (((k >> 6) & 1) << 4);
        float4 v0 = src[0], v1 = src[1], v2 = src[2], v3 = src[3];
        *reinterpret_cast<float4*>(&w_lds[base + 0]) = v0;
        *reinterpret_cast<float4*>(&w_lds[base + 4]) = v1;
        *reinterpret_cast<float4*>(&w_lds[base + 8]) = v2;
        *reinterpret_cast<float4*>(&w_lds[base + 12]) = v3;
    }
    __syncthreads();

    int wid = t >> 6;
    int d = blockIdx.x * 4 + wid;
    if (d >= N) return;
    int lane = t & 63;
    int head = lane >> 3;
    int po = lane >> 3;
    int ph = lane & 7;
    float ad_p = ad1[d * 8 + ph];
    int beg = offs[d], end = offs[d + 1];
    float denom = 0.f, a0 = 0.f, a1 = 0.f, a2 = 0.f, a3 = 0.f;
    for (int cb = beg; cb < end; cb += 64) {
        int idx = cb + lane;
        int myS = srcs[idx < end ? idx : end - 1];
        int cnt = min(64, end - cb);   // wave-uniform
        float p8[8];
        #pragma unroll
        for (int j = 0; j < 8; ++j) {
            int s = __shfl(myS, po * 8 + j);
            p8[j] = __expf(leaky02(as1[s * 8 + ph] + ad_p));
        }
        for (int kb = 0; kb < cnt; kb += 8) {
            #pragma unroll
            for (int j = 0; j < 8; ++j) {
                int k = kb + j;            // wave-uniform
                if (k < cnt) {             // uniform branch: convergent shfls
                    int s = __shfl(myS, k);
                    float p = __shfl(p8[j], kb + head);
                    denom += p;
                    uint2 raw = *reinterpret_cast<const uint2*>(
                        h1h + (size_t)s * 256 + lane * 4);
                    union { unsigned u; __half2 h; } u0, u1;
                    u0.u = raw.x; u1.u = raw.y;
                    float2 f01 = __half22float2(u0.h);
                    float2 f23 = __half22float2(u1.h);
                    a0 += p * f01.x; a1 += p * f01.y;
                    a2 += p * f23.x; a3 += p * f23.y;
                }
            }
        }
    }
    float inv = 1.f / (denom + 1e-16f);
    int c = lane * 4;
    float4 bv = *reinterpret_cast<const float4*>(&b1[c]);
    float r0 = a0 * inv + bv.x;
    float r1 = a1 * inv + bv.y;
    float r2 = a2 * inv + bv.z;
    float r3 = a3 * inv + bv.w;
    r0 = r0 > 0.f ? r0 : (__expf(r0) - 1.f);
    r1 = r1 > 0.f ? r1 : (__expf(r1) - 1.f);
    r2 = r2 > 0.f ? r2 : (__expf(r2) - 1.f);
    r3 = r3 > 0.f ? r3 : (__expf(r3) - 1.f);
    // ---- node2 tail: feat -> LDS (wave-private row; no barrier needed) ----
    float4 fv; fv.x = r0; fv.y = r1; fv.z = r2; fv.w = r3;
    *reinterpret_cast<float4*>(&feat_lds[wid * 256 + c]) = fv;
    int o = lane & 15, q = lane >> 4;
    const float* fl = &feat_lds[wid * 256 + q * 64];
    const float* w = w_lds + ((q >> 1) << 11) + ((q & 1) << 4) + o;  // + j*32
    float acc = 0.f;
    #pragma unroll 8
    for (int j = 0; j < 64; ++j)
        acc += fl[j] * w[j * 32];
    acc += __shfl_xor(acc, 16);
    acc += __shfl_xor(acc, 32);    // all lanes hold h2[d][o]
    if (lane < 16) h2h[d * 16 + o] = __float2half(acc);
    float ts = acc * att_s2[o], td = acc * att_d2[o];
    #pragma unroll
    for (int m = 1; m < 16; m <<= 1) {
        ts += __shfl_xor(ts, m);
        td += __shfl_xor(td, m);
    }
    if (lane == 0) { as2[d] = ts; ad2[d] = td; }
}

// K_agg2: one wave per dst. 16 edge-groups x 4 lanes owning 4 channels each.
// All lanes execute every shfl (convergent); accumulate predicated only.
__global__ void k_agg2(const __half* __restrict__ h2h, const float* __restrict__ as2,
                       const float* __restrict__ ad2, const float* __restrict__ b2,
                       const int* __restrict__ offs, const int* __restrict__ srcs,
                       float* __restrict__ out, int N) {
    int wid = threadIdx.x >> 6;
    int d = blockIdx.x * 4 + wid;
    if (d >= N) return;
    int lane = threadIdx.x & 63;
    int cl = lane & 3, eg = lane >> 2;
    float ad = ad2[d];
    int beg = offs[d], end = offs[d + 1];
    float denom = 0.f, a0 = 0.f, a1 = 0.f, a2 = 0.f, a3 = 0.f;
    for (int cb = beg; cb < end; cb += 64) {
        int idx = cb + lane;
        int myS = srcs[idx < end ? idx : end - 1];
        #pragma unroll
        for (int cc = 0; cc < 4; ++cc) {
            int s = __shfl(myS, cc * 16 + eg);   // convergent
            int epos = cb + cc * 16 + eg;
            if (epos < end) {
                float e = leaky02(as2[s] + ad);
                float p = __expf(e);
                denom += p;
                uint2 raw = *reinterpret_cast<const uint2*>(h2h + (size_t)s * 16 + cl * 4);
                union { unsigned u; __half2 h; } u0, u1;
                u0.u = raw.x; u1.u = raw.y;
                float2 f01 = __half22float2(u0.h);
                float2 f23 = __half22float2(u1.h);
                a0 += p * f01.x; a1 += p * f01.y; a2 += p * f23.x; a3 += p * f23.y;
            }
        }
    }
    #pragma unroll
    for (int m = 4; m < 64; m <<= 1) {
        denom += __shfl_xor(denom, m);
        a0 += __shfl_xor(a0, m);
        a1 += __shfl_xor(a1, m);
        a2 += __shfl_xor(a2, m);
        a3 += __shfl_xor(a3, m);
    }
    if (eg == 0) {
        float inv = 1.f / (denom + 1e-16f);
        int c = cl * 4;
        float4 r;
        r.x = a0 * inv + b2[c + 0];
        r.y = a1 * inv + b2[c + 1];
        r.z = a2 * inv + b2[c + 2];
        r.w = a3 * inv + b2[c + 3];
        *reinterpret_cast<float4*>(&out[d * 16 + c]) = r;
    }
}

extern "C" void kernel_launch(void* const* d_in, const int* in_sizes, int n_in,
                              void* d_out, int out_size, void* d_ws, size_t ws_size,
                              hipStream_t stream) {
    const float* x       = (const float*)d_in[0];
    const int*   ei      = (const int*)d_in[1];
    const float* W1      = (const float*)d_in[2];
    const float* att_s1  = (const float*)d_in[3];
    const float* att_d1  = (const float*)d_in[4];
    const float* b1      = (const float*)d_in[5];
    const float* W2      = (const float*)d_in[6];
    const float* att_s2  = (const float*)d_in[7];
    const float* att_d2  = (const float*)d_in[8];
    const float* b2      = (const float*)d_in[9];
    float* out = (float*)d_out;

    const int N = in_sizes[0] / 3;
    const int E = in_sizes[1] / 2;
    const int Etot = E + N;
    const int NB = (N + 1023) / 1024;  // scan blocks

    // carve workspace (16B aligned slices)
    char* w = (char*)d_ws;
    auto alloc = [&](size_t bytes) -> void* {
        void* p = (void*)w;
        w += (bytes + 15) & ~(size_t)15;
        return p;
    };
    int* counts   = (int*)alloc((size_t)N * 4);
    int* offs     = (int*)alloc((size_t)(N + 1) * 4);
    int* cursor   = (int*)alloc((size_t)N * 4);
    int* srcs     = (int*)alloc((size_t)Etot * 4);
    int* bsum     = (int*)alloc((size_t)(NB + 1) * 4);
    __half* h1h   = (__half*)alloc((size_t)N * 256 * 2);
    float* as1    = (float*)alloc((size_t)N * 8 * 4);
    float* ad1    = (float*)alloc((size_t)N * 8 * 4);
    __half* h2h   = (__half*)alloc((size_t)N * 16 * 2);
    float* as2    = (float*)alloc((size_t)N * 4);
    float* ad2    = (float*)alloc((size_t)N * 4);
    (void)ws_size; (void)n_in; (void)out_size;

    const int B = 256;
    const int NB1 = (N + 3) / 4;            // node1 blocks in k_prep
    const int NBc = (E + B - 1) / B;        // count blocks in k_prep

    hipMemsetAsync(counts, 0, (size_t)N * 4, stream);
    hipLaunchKernelGGL(k_prep, dim3(NB1 + NBc), dim3(B), 0, stream,
                       x, W1, att_s1, att_d1, h1h, as1, ad1, ei, counts, N, E, NB1);
    hipLaunchKernelGGL(k_bsum, dim3(NB), dim3(B), 0, stream, counts, bsum, N);
    hipLaunchKernelGGL(k_offs, dim3(NB), dim3(B), 0, stream, counts, bsum, offs, cursor, N, NB);
    hipLaunchKernelGGL(k_scatter, dim3((Etot + B - 1) / B), dim3(B), 0, stream,
                       ei, cursor, srcs, E, N);
    hipLaunchKernelGGL(k_agg1n2, dim3((N + 3) / 4), dim3(B), 0, stream,
                       h1h, as1, ad1, b1, W2, att_s2, att_d2, offs, srcs,
                       h2h, as2, ad2, N);
    hipLaunchKernelGGL(k_agg2, dim3((N + 3) / 4), dim3(B), 0, stream,
                       h2h, as2, ad2, b2, offs, srcs, out, N);
}